// Round 5
// baseline (836.135 us; speedup 1.0000x reference)
//
#include <hip/hip_runtime.h>
#include <math.h>

#define TT 512
#define BB 256
#define OBSZ 128
#define HH 64
#define G3 192
#define NROW (TT*BB)
#define TSPLIT 4
#define TCH (TT/TSPLIT)

// ---- fast transcendentals: ONLY used downstream of sign() (MLP heads) -----
__device__ __forceinline__ float fast_rcp(float x) {
    return __builtin_amdgcn_rcpf(x);
}
__device__ __forceinline__ float tanh_fast(float x) {
    float xc = fminf(fmaxf(x, -20.0f), 20.0f);   // clamp: avoid inf/inf NaN
    float e2 = __expf(2.0f * xc);
    return (e2 - 1.0f) * fast_rcp(e2 + 1.0f);
}

// ---------------------------------------------------------------------------
// gi projection: gi_all[t,b,g] = w_ih[g,:].x[t,b,:] + b_ih[g]
// Chain order BIT-IDENTICAL to the (passing) fused scan: 4 float4 chains
// g0..g3 over k4 ascending, final bi + ((g0+g1)+(g2+g3)).
// 256 threads: tau<192 weight-stationary (asm-keep blocks rematerialization
// -- round-3/4 CSVs proved the compiler re-loads weight arrays from L2 every
// iter instead of keeping them in VGPRs), tau>=192 stage x rows depth-4.
// ---------------------------------------------------------------------------
__global__ __launch_bounds__(256, 1)
__attribute__((amdgpu_waves_per_eu(1, 2)))
void gi_proj_kernel(const float* __restrict__ x,
                    const float* __restrict__ w_ih, const float* __restrict__ b_ih,
                    float* __restrict__ gi_ws)
{
    const int b   = blockIdx.x;
    const int t0  = blockIdx.y * TCH;
    const int tau = threadIdx.x;

    __shared__ __align__(16) float xb[4][OBSZ];

    float4 wi4[OBSZ/4];
    float bi = 0.f;
    float2 p0, p1, p2;
    if (tau < G3) {
        const float4* wip = (const float4*)(w_ih + tau*OBSZ);
        #pragma unroll
        for (int k4 = 0; k4 < OBSZ/4; ++k4) wi4[k4] = wip[k4];
        #pragma unroll
        for (int k4 = 0; k4 < OBSZ/4; ++k4)
            asm volatile("" : "+v"(wi4[k4].x), "+v"(wi4[k4].y),
                              "+v"(wi4[k4].z), "+v"(wi4[k4].w));
        bi = b_ih[tau];
    } else {
        const int k0 = (tau - G3)*2;
        float2 v = *(const float2*)(x + (size_t)((t0+0)*BB + b)*OBSZ + k0);
        xb[0][k0] = v.x; xb[0][k0+1] = v.y;
        p0 = *(const float2*)(x + (size_t)((t0+1)*BB + b)*OBSZ + k0);
        p1 = *(const float2*)(x + (size_t)((t0+2)*BB + b)*OBSZ + k0);
        p2 = *(const float2*)(x + (size_t)((t0+3)*BB + b)*OBSZ + k0);
    }
    __syncthreads();

    for (int tt = 0; tt < TCH; ++tt) {
        if (tau < G3) {
            const float4* xb4 = (const float4*)xb[tt & 3];
            float g0=0.f, g1=0.f, g2=0.f, g3=0.f;
            #pragma unroll
            for (int k4 = 0; k4 < OBSZ/4; ++k4) {
                float4 xv = xb4[k4];
                g0 = fmaf(xv.x, wi4[k4].x, g0);
                g1 = fmaf(xv.y, wi4[k4].y, g1);
                g2 = fmaf(xv.z, wi4[k4].z, g2);
                g3 = fmaf(xv.w, wi4[k4].w, g3);
            }
            float gi = bi + ((g0+g1)+(g2+g3));
            gi_ws[((size_t)(t0+tt)*BB + b)*G3 + tau] = gi;
        } else {
            const int k0 = (tau - G3)*2;
            if (tt+1 < TCH) { xb[(tt+1)&3][k0] = p0.x; xb[(tt+1)&3][k0+1] = p0.y; }
            p0 = p1; p1 = p2;
            if (tt+4 < TCH)
                p2 = *(const float2*)(x + (size_t)((t0+tt+4)*BB + b)*OBSZ + k0);
        }
        __syncthreads();
    }
}

// ---------------------------------------------------------------------------
// Light GRU scan: gh = w_hh . h only (gi streamed from workspace, depth-2
// prefetch). One block per batch element. tau<192: w_hh row (64 f32 -> ~100
// VGPR, under the 120 budget, no remat pressure). tau>=192: gate threads
// (libm expf/tanhf -- precision-critical upstream of sign(); fast versions
// flipped signs -> 0.45 FAIL, measured round 2).
// All arithmetic bit-identical to passing rounds 3/4.
// ---------------------------------------------------------------------------
__global__ __launch_bounds__(256, 1)
void scan_kernel(const float* __restrict__ gi_ws, const float* __restrict__ h0,
                 const float* __restrict__ done,
                 const float* __restrict__ w_hh, const float* __restrict__ b_hh,
                 signed char* __restrict__ hidden, float* __restrict__ state_out)
{
    const int b   = blockIdx.x;
    const int tau = threadIdx.x;

    __shared__ __align__(16) float hb[HH];
    __shared__ __align__(16) float srz[2*HH];
    __shared__ __align__(16) float sinb[HH];
    __shared__ __align__(16) float shnb[HH];

    float4 wh4[HH/4];
    float bh = 0.f;
    float gp0 = 0.f, gp1 = 0.f;
    if (tau < G3) {
        const float4* whp = (const float4*)(w_hh + tau*HH);
        #pragma unroll
        for (int j4 = 0; j4 < HH/4; ++j4) wh4[j4] = whp[j4];
        #pragma unroll
        for (int j4 = 0; j4 < HH/4; ++j4)
            asm volatile("" : "+v"(wh4[j4].x), "+v"(wh4[j4].y),
                              "+v"(wh4[j4].z), "+v"(wh4[j4].w));
        bh = b_hh[tau];
        gp0 = gi_ws[((size_t)0*BB + b)*G3 + tau];
        gp1 = gi_ws[((size_t)1*BB + b)*G3 + tau];
    } else {
        const int hl = tau - G3;
        float d0 = done[0*BB + b];
        hb[hl] = (1.0f - d0) * h0[b*HH + hl];
    }
    __syncthreads();

    float dnext = 0.f;
    for (int t = 0; t < TT; ++t) {
        if (tau < G3) {
            float gi = gp0;
            gp0 = gp1;
            if (t+2 < TT) gp1 = gi_ws[((size_t)(t+2)*BB + b)*G3 + tau];
            // gh = w_hh[g,:] . h (+b_hh): chains identical to rounds 3/4
            const float4* hb4 = (const float4*)hb;
            float a0=0.f, a1=0.f, a2=0.f, a3=0.f;
            #pragma unroll
            for (int j4 = 0; j4 < HH/4; ++j4) {
                float4 hv = hb4[j4];
                a0 = fmaf(hv.x, wh4[j4].x, a0);
                a1 = fmaf(hv.y, wh4[j4].y, a1);
                a2 = fmaf(hv.z, wh4[j4].z, a2);
                a3 = fmaf(hv.w, wh4[j4].w, a3);
            }
            float gh = bh + ((a0+a1)+(a2+a3));
            if (tau < 2*HH) srz[tau] = gi + gh;
            else { sinb[tau-2*HH] = gi; shnb[tau-2*HH] = gh; }
        } else {
            if (t+1 < TT) dnext = done[(t+1)*BB + b];
        }
        __syncthreads();   // (A) srz/sin/shn ready; hb reads complete

        if (tau >= G3) {
            const int hl = tau - G3;
            float sr = srz[hl];
            float sz = srz[HH + hl];
            float r = 1.0f / (1.0f + expf(-sr));   // libm: precision-critical
            float z = 1.0f / (1.0f + expf(-sz));
            float n = tanhf(sinb[hl] + r * shnb[hl]);
            float hm = hb[hl];
            float hnew = (1.0f - z)*n + z*hm;
            float s = (hnew > 0.f) ? 1.f : ((hnew < 0.f) ? -1.f : 0.f);
            hidden[(size_t)(t*BB + b)*HH + hl] = (signed char)s;
            if (t == TT-1) state_out[b*HH + hl] = s;
            hb[hl] = (t+1 < TT && dnext != 0.f) ? 0.f : s;
        }
        __syncthreads();   // (B) hb ready for next step
    }
}

// ---------------------------------------------------------------------------
// Fallback fused scan (round-4 verbatim) for when ws_size < gi_all + hidden.
// ---------------------------------------------------------------------------
__global__ __launch_bounds__(256, 1)
void scan_kernel_fused(const float* __restrict__ x, const float* __restrict__ h0,
                       const float* __restrict__ done,
                       const float* __restrict__ w_ih, const float* __restrict__ w_hh,
                       const float* __restrict__ b_ih, const float* __restrict__ b_hh,
                       signed char* __restrict__ hidden, float* __restrict__ state_out)
{
    const int b   = blockIdx.x;
    const int tau = threadIdx.x;

    __shared__ __align__(16) float xb[2][OBSZ];
    __shared__ __align__(16) float hb[HH];
    __shared__ __align__(16) float srz[2*HH];
    __shared__ __align__(16) float sinb[HH];
    __shared__ __align__(16) float shnb[HH];

    float4 wi4[OBSZ/4];
    float4 wh4[HH/4];
    float bi = 0.f, bh = 0.f;
    if (tau < G3) {
        const float4* wip = (const float4*)(w_ih + tau*OBSZ);
        #pragma unroll
        for (int k4 = 0; k4 < OBSZ/4; ++k4) wi4[k4] = wip[k4];
        const float4* whp = (const float4*)(w_hh + tau*HH);
        #pragma unroll
        for (int j4 = 0; j4 < HH/4; ++j4) wh4[j4] = whp[j4];
        bi = b_ih[tau]; bh = b_hh[tau];
    } else {
        const int hl = tau - G3;
        const int k0 = hl*2;
        float2 v = *(const float2*)(x + (size_t)(0*BB + b)*OBSZ + k0);
        xb[0][k0] = v.x; xb[0][k0+1] = v.y;
        float d0 = done[0*BB + b];
        hb[hl] = (1.0f - d0) * h0[b*HH + hl];
    }
    __syncthreads();

    float dnext = 0.f;
    for (int t = 0; t < TT; ++t) {
        const int cur = t & 1, nxt = cur ^ 1;
        if (tau < G3) {
            const float4* hb4 = (const float4*)hb;
            float a0=0.f, a1=0.f, a2=0.f, a3=0.f;
            #pragma unroll
            for (int j4 = 0; j4 < HH/4; ++j4) {
                float4 hv = hb4[j4];
                a0 = fmaf(hv.x, wh4[j4].x, a0);
                a1 = fmaf(hv.y, wh4[j4].y, a1);
                a2 = fmaf(hv.z, wh4[j4].z, a2);
                a3 = fmaf(hv.w, wh4[j4].w, a3);
            }
            float gh = bh + ((a0+a1)+(a2+a3));
            const float4* xb4 = (const float4*)xb[cur];
            float g0=0.f, g1=0.f, g2=0.f, g3=0.f;
            #pragma unroll
            for (int k4 = 0; k4 < OBSZ/4; ++k4) {
                float4 xv = xb4[k4];
                g0 = fmaf(xv.x, wi4[k4].x, g0);
                g1 = fmaf(xv.y, wi4[k4].y, g1);
                g2 = fmaf(xv.z, wi4[k4].z, g2);
                g3 = fmaf(xv.w, wi4[k4].w, g3);
            }
            float gi = bi + ((g0+g1)+(g2+g3));
            if (tau < 2*HH) srz[tau] = gi + gh;
            else { sinb[tau-2*HH] = gi; shnb[tau-2*HH] = gh; }
        } else {
            const int hl = tau - G3;
            if (t+1 < TT) {
                const int k0 = hl*2;
                float2 xr = *(const float2*)(x + (size_t)((t+1)*BB + b)*OBSZ + k0);
                xb[nxt][k0] = xr.x; xb[nxt][k0+1] = xr.y;
                dnext = done[(t+1)*BB + b];
            }
        }
        __syncthreads();

        if (tau >= G3) {
            const int hl = tau - G3;
            float sr = srz[hl];
            float sz = srz[HH + hl];
            float r = 1.0f / (1.0f + expf(-sr));
            float z = 1.0f / (1.0f + expf(-sz));
            float n = tanhf(sinb[hl] + r * shnb[hl]);
            float hm = hb[hl];
            float hnew = (1.0f - z)*n + z*hm;
            float s = (hnew > 0.f) ? 1.f : ((hnew < 0.f) ? -1.f : 0.f);
            hidden[(size_t)(t*BB + b)*HH + hl] = (signed char)s;
            if (t == TT-1) state_out[b*HH + hl] = s;
            hb[hl] = (t+1 < TT && dnext != 0.f) ? 0.f : s;
        }
        __syncthreads();
    }
}

// ---------------------------------------------------------------------------
// Fused 3-layer MLP over cat=[hidden(s8,64), x(f32,128)].  (unchanged, r3)
// ---------------------------------------------------------------------------
template<int NOUT>
__global__ __launch_bounds__(256, 2)
void mlp_kernel(const signed char* __restrict__ hidden, const float* __restrict__ x,
                const float* __restrict__ w1, const float* __restrict__ b1,
                const float* __restrict__ w2, const float* __restrict__ b2,
                const float* __restrict__ w3, const float* __restrict__ b3,
                float* __restrict__ out)
{
    __shared__ __align__(16) float wbuf[64*100];   // 25.6 KB (w1-half / w2 / w3)
    __shared__ __align__(16) float ybuf[128*68];   // 34.8 KB (y1 then y2)
    const int tid = threadIdx.x;
    const int g   = tid >> 3;   // lane-group 0..31 (4 rows each)
    const int q   = tid & 7;    // feature lane

    float bv1[8], bv2[8];
    #pragma unroll
    for (int j = 0; j < 8; ++j) { bv1[j] = b1[q + 8*j]; bv2[j] = b2[q + 8*j]; }

    for (int chunk = 0; chunk < 2; ++chunk) {
        const int row0 = blockIdx.x*256 + chunk*128 + g*4;

        float acc[8][4];
        #pragma unroll
        for (int j = 0; j < 8; ++j)
            #pragma unroll
            for (int r = 0; r < 4; ++r) acc[j][r] = bv1[j];

        auto dot8 = [&](float (&cv)[4][8], int colbase) {
            #pragma unroll
            for (int j = 0; j < 8; ++j) {
                const float* wp = &wbuf[(q + 8*j)*100 + colbase];
                float4 w0 = *(const float4*)wp;
                float4 w1v = *(const float4*)(wp + 4);
                #pragma unroll
                for (int r = 0; r < 4; ++r) {
                    acc[j][r] = fmaf(cv[r][0], w0.x,  acc[j][r]);
                    acc[j][r] = fmaf(cv[r][1], w0.y,  acc[j][r]);
                    acc[j][r] = fmaf(cv[r][2], w0.z,  acc[j][r]);
                    acc[j][r] = fmaf(cv[r][3], w0.w,  acc[j][r]);
                    acc[j][r] = fmaf(cv[r][4], w1v.x, acc[j][r]);
                    acc[j][r] = fmaf(cv[r][5], w1v.y, acc[j][r]);
                    acc[j][r] = fmaf(cv[r][6], w1v.z, acc[j][r]);
                    acc[j][r] = fmaf(cv[r][7], w1v.w, acc[j][r]);
                }
            }
        };

        #pragma unroll
        for (int half = 0; half < 2; ++half) {
            __syncthreads();   // prior wbuf/ybuf readers done before restage
            #pragma unroll
            for (int i = 0; i < 6; ++i) {          // stage w1 half [64][96]->stride 100
                int v = tid + i*256;
                int f = v / 24, k4 = v % 24;
                *(float4*)&wbuf[f*100 + k4*4] =
                    *(const float4*)&w1[f*G3 + half*96 + k4*4];
            }
            __syncthreads();

            if (half == 0) {
                for (int kc = 0; kc < 8; ++kc) {   // k 0..63: hidden (s8)
                    float cv[4][8];
                    #pragma unroll
                    for (int r = 0; r < 4; ++r) {
                        uint2 hv = *(const uint2*)(hidden + (size_t)(row0+r)*HH + kc*8);
                        cv[r][0] = (float)(signed char)(hv.x);
                        cv[r][1] = (float)(signed char)(hv.x >> 8);
                        cv[r][2] = (float)(signed char)(hv.x >> 16);
                        cv[r][3] = (float)(signed char)(hv.x >> 24);
                        cv[r][4] = (float)(signed char)(hv.y);
                        cv[r][5] = (float)(signed char)(hv.y >> 8);
                        cv[r][6] = (float)(signed char)(hv.y >> 16);
                        cv[r][7] = (float)(signed char)(hv.y >> 24);
                    }
                    dot8(cv, kc*8);
                }
                for (int kc = 0; kc < 4; ++kc) {   // k 64..95: x[0..31]
                    float cv[4][8];
                    #pragma unroll
                    for (int r = 0; r < 4; ++r) {
                        const float* xp = x + (size_t)(row0+r)*OBSZ + kc*8;
                        float4 a = *(const float4*)xp;
                        float4 c = *(const float4*)(xp + 4);
                        cv[r][0]=a.x; cv[r][1]=a.y; cv[r][2]=a.z; cv[r][3]=a.w;
                        cv[r][4]=c.x; cv[r][5]=c.y; cv[r][6]=c.z; cv[r][7]=c.w;
                    }
                    dot8(cv, 64 + kc*8);
                }
            } else {
                for (int kc = 0; kc < 12; ++kc) {  // k 96..191: x[32..127]
                    float cv[4][8];
                    #pragma unroll
                    for (int r = 0; r < 4; ++r) {
                        const float* xp = x + (size_t)(row0+r)*OBSZ + 32 + kc*8;
                        float4 a = *(const float4*)xp;
                        float4 c = *(const float4*)(xp + 4);
                        cv[r][0]=a.x; cv[r][1]=a.y; cv[r][2]=a.z; cv[r][3]=a.w;
                        cv[r][4]=c.x; cv[r][5]=c.y; cv[r][6]=c.z; cv[r][7]=c.w;
                    }
                    dot8(cv, kc*8);
                }
            }
        }

        #pragma unroll
        for (int j = 0; j < 8; ++j)
            #pragma unroll
            for (int r = 0; r < 4; ++r)
                ybuf[(g*4+r)*68 + q + 8*j] = tanh_fast(acc[j][r]);
        __syncthreads();

        #pragma unroll
        for (int i = 0; i < 4; ++i) {              // stage w2 [64][64]->stride 68
            int v = tid + i*256;
            int f = v >> 4, k4 = v & 15;
            *(float4*)&wbuf[f*68 + k4*4] = *(const float4*)&w2[f*HH + k4*4];
        }
        __syncthreads();

        float acc2[8][4];
        #pragma unroll
        for (int j = 0; j < 8; ++j)
            #pragma unroll
            for (int r = 0; r < 4; ++r) acc2[j][r] = bv2[j];

        for (int kc = 0; kc < 8; ++kc) {
            float cv[4][8];
            #pragma unroll
            for (int r = 0; r < 4; ++r) {
                const float* yp = &ybuf[(g*4+r)*68 + kc*8];
                float4 a = *(const float4*)yp;
                float4 c = *(const float4*)(yp + 4);
                cv[r][0]=a.x; cv[r][1]=a.y; cv[r][2]=a.z; cv[r][3]=a.w;
                cv[r][4]=c.x; cv[r][5]=c.y; cv[r][6]=c.z; cv[r][7]=c.w;
            }
            #pragma unroll
            for (int j = 0; j < 8; ++j) {
                const float* wp = &wbuf[(q + 8*j)*68 + kc*8];
                float4 w0 = *(const float4*)wp;
                float4 w1v = *(const float4*)(wp + 4);
                #pragma unroll
                for (int r = 0; r < 4; ++r) {
                    acc2[j][r] = fmaf(cv[r][0], w0.x,  acc2[j][r]);
                    acc2[j][r] = fmaf(cv[r][1], w0.y,  acc2[j][r]);
                    acc2[j][r] = fmaf(cv[r][2], w0.z,  acc2[j][r]);
                    acc2[j][r] = fmaf(cv[r][3], w0.w,  acc2[j][r]);
                    acc2[j][r] = fmaf(cv[r][4], w1v.x, acc2[j][r]);
                    acc2[j][r] = fmaf(cv[r][5], w1v.y, acc2[j][r]);
                    acc2[j][r] = fmaf(cv[r][6], w1v.z, acc2[j][r]);
                    acc2[j][r] = fmaf(cv[r][7], w1v.w, acc2[j][r]);
                }
            }
        }
        __syncthreads();   // all y1 reads done before overwrite

        #pragma unroll
        for (int j = 0; j < 8; ++j)
            #pragma unroll
            for (int r = 0; r < 4; ++r)
                ybuf[(g*4+r)*68 + q + 8*j] = tanh_fast(acc2[j][r]);
        if (tid < NOUT*16) {                       // stage w3 [NOUT][64]->stride 68
            int f = tid >> 4, k4 = tid & 15;
            *(float4*)&wbuf[f*68 + k4*4] = *(const float4*)&w3[f*HH + k4*4];
        }
        __syncthreads();

        #pragma unroll
        for (int oo = 0; oo < (NOUT + 7)/8; ++oo) {
            const int o = q + 8*oo;
            if (o < NOUT) {
                #pragma unroll
                for (int r = 0; r < 4; ++r) {
                    const float* yp = &ybuf[(g*4+r)*68];
                    const float* wp = &wbuf[o*68];
                    float s0=0.f, s1=0.f, s2=0.f, s3=0.f;
                    #pragma unroll
                    for (int k4 = 0; k4 < 16; ++k4) {
                        float4 yv = *(const float4*)(yp + k4*4);
                        float4 wv = *(const float4*)(wp + k4*4);
                        s0 = fmaf(yv.x, wv.x, s0);
                        s1 = fmaf(yv.y, wv.y, s1);
                        s2 = fmaf(yv.z, wv.z, s2);
                        s3 = fmaf(yv.w, wv.w, s3);
                    }
                    out[(size_t)(row0+r)*NOUT + o] = b3[o] + ((s0+s1)+(s2+s3));
                }
            }
        }
        __syncthreads();   // layer3 ybuf/wbuf reads done before next chunk
    }
}

extern "C" void kernel_launch(void* const* d_in, const int* in_sizes, int n_in,
                              void* d_out, int out_size, void* d_ws, size_t ws_size,
                              hipStream_t stream) {
    const float* x     = (const float*)d_in[0];
    const float* h0    = (const float*)d_in[1];
    const float* done  = (const float*)d_in[2];
    const float* w_ih  = (const float*)d_in[3];
    const float* w_hh  = (const float*)d_in[4];
    const float* b_ih  = (const float*)d_in[5];
    const float* b_hh  = (const float*)d_in[6];
    const float* a_w1  = (const float*)d_in[7];
    const float* a_b1  = (const float*)d_in[8];
    const float* a_w2  = (const float*)d_in[9];
    const float* a_b2  = (const float*)d_in[10];
    const float* a_w3  = (const float*)d_in[11];
    const float* a_b3  = (const float*)d_in[12];
    const float* c_w1  = (const float*)d_in[13];
    const float* c_b1  = (const float*)d_in[14];
    const float* c_w2  = (const float*)d_in[15];
    const float* c_b2  = (const float*)d_in[16];
    const float* c_w3  = (const float*)d_in[17];
    const float* c_b3  = (const float*)d_in[18];

    float* out    = (float*)d_out;
    float* logits = out;                       // [131072, 16]
    float* value  = out + (size_t)NROW*16;     // [131072]
    float* state  = value + NROW;              // [1, 256, 64]

    signed char* hidden = (signed char*)d_ws;  // [131072, 64] in {-1,0,1}
    const size_t hidden_bytes = (size_t)NROW * HH;
    const size_t gi_bytes     = (size_t)NROW * G3 * sizeof(float);

    if (ws_size >= hidden_bytes + gi_bytes) {
        float* gi_ws = (float*)((char*)d_ws + hidden_bytes);
        gi_proj_kernel<<<dim3(BB, TSPLIT), 256, 0, stream>>>(x, w_ih, b_ih, gi_ws);
        scan_kernel<<<BB, 256, 0, stream>>>(gi_ws, h0, done, w_hh, b_hh,
                                            hidden, state);
    } else {
        scan_kernel_fused<<<BB, 256, 0, stream>>>(x, h0, done, w_ih, w_hh,
                                                  b_ih, b_hh, hidden, state);
    }
    mlp_kernel<16><<<512, 256, 0, stream>>>(hidden, x, a_w1, a_b1, a_w2, a_b2,
                                            a_w3, a_b3, logits);
    mlp_kernel<1><<<512, 256, 0, stream>>>(hidden, x, c_w1, c_b1, c_w2, c_b2,
                                           c_w3, c_b3, value);
}